// Round 1
// baseline (765.879 us; speedup 1.0000x reference)
//
#include <hip/hip_runtime.h>
#include <hip/hip_bf16.h>

#define EPS 1e-5f

// ---------------------------------------------------------------------------
// K1: integer degree histograms
__global__ void degrees_kernel(const int* __restrict__ src, const int* __restrict__ dst,
                               int* __restrict__ outdeg, int* __restrict__ indeg, int E) {
    int i = blockIdx.x * blockDim.x + threadIdx.x;
    if (i < E) {
        atomicAdd(&outdeg[src[i]], 1);
        atomicAdd(&indeg[dst[i]], 1);
    }
}

// K2: normalization factors rsqrt(max(deg,1))
__global__ void norms_kernel(const int* __restrict__ outdeg, const int* __restrict__ indeg,
                             float* __restrict__ nsrc, float* __restrict__ ndst, int n) {
    int i = blockIdx.x * blockDim.x + threadIdx.x;
    if (i < n) {
        nsrc[i] = rsqrtf((float)max(outdeg[i], 1));
        ndst[i] = rsqrtf((float)max(indeg[i], 1));
    }
}

// K3: exclusive scan of in-degrees -> CSC offsets. Single block, 1024 threads,
// wave-shuffle scan (no O(n) barrier chains).
__global__ __launch_bounds__(1024) void scan_offsets_kernel(const int* __restrict__ deg,
                                                            int* __restrict__ offs, int n) {
    __shared__ int wsum[16];
    __shared__ int carry_s;
    int tid = threadIdx.x, lane = tid & 63, wid = tid >> 6;
    if (tid == 0) carry_s = 0;
    __syncthreads();
    for (int base = 0; base < n; base += 1024) {
        int i = base + tid;
        int v = (i < n) ? deg[i] : 0;
        int x = v;
        #pragma unroll
        for (int off = 1; off < 64; off <<= 1) {
            int t = __shfl_up(x, off, 64);
            if (lane >= off) x += t;
        }
        if (lane == 63) wsum[wid] = x;
        __syncthreads();
        if (wid == 0) {
            int w = (lane < 16) ? wsum[lane] : 0;
            #pragma unroll
            for (int off = 1; off < 16; off <<= 1) {
                int t = __shfl_up(w, off, 64);
                if (lane >= off) w += t;
            }
            if (lane < 16) wsum[lane] = w;
        }
        __syncthreads();
        int carry = carry_s;
        int wpre = (wid > 0) ? wsum[wid - 1] : 0;
        if (i < n) offs[i] = carry + wpre + (x - v);
        __syncthreads();
        if (tid == 0) carry_s = carry + wsum[15];
        __syncthreads();
    }
    if (threadIdx.x == 0) offs[n] = carry_s;
}

// K4: scatter edges into CSC slots (order within a node is atomic-nondeterministic;
// only affects fp32 summation order -> ~1e-6, far below 4.2e-3 threshold)
__global__ void fill_csc_kernel(const int* __restrict__ src, const int* __restrict__ dst,
                                const int* __restrict__ offs, int* __restrict__ cursor,
                                int* __restrict__ csc, int E) {
    int i = blockIdx.x * blockDim.x + threadIdx.x;
    if (i < E) {
        int d = dst[i];
        int p = atomicAdd(&cursor[d], 1);
        csc[offs[d] + p] = src[i];
    }
}

// ---------------------------------------------------------------------------
// K5: fp32 GEMM  C[M,128] (=|+=) (A[M,128] * rowscale) @ B[128,128] (+ colbias)
// Block: 256 threads, tile 64 rows x 64 cols (grid.y=2 col halves), 4x4 micro-tile.
__global__ __launch_bounds__(256) void gemm128_kernel(
    const float* __restrict__ A, const float* __restrict__ B, float* __restrict__ C,
    const float* __restrict__ rowscale, const float* __restrict__ colbias,
    int M, int accumulate) {
    __shared__ __align__(16) float As[64][132];   // padded pitch
    __shared__ __align__(16) float Bs[128][64];
    const int row0 = blockIdx.x * 64;
    const int cb = blockIdx.y;           // 0/1 column half
    const int tid = threadIdx.x;

    // stage B column-half: 128x64 floats
    {
        const float* Bsrc = B + cb * 64;
        for (int idx = tid; idx < 128 * 16; idx += 256) {
            int k = idx >> 4;
            int j = (idx & 15) << 2;
            float4 v = *(const float4*)(Bsrc + k * 128 + j);
            *(float4*)&Bs[k][j] = v;
        }
    }
    // stage A tile (64 rows x 128 cols), fused row-scale
    {
        for (int idx = tid; idx < 64 * 32; idx += 256) {
            int m = idx >> 5;
            int j = (idx & 31) << 2;
            int row = row0 + m;
            float4 v = make_float4(0.f, 0.f, 0.f, 0.f);
            float s = 1.0f;
            if (row < M) {
                v = *(const float4*)(A + (size_t)row * 128 + j);
                if (rowscale) s = rowscale[row];
            }
            float4 w = make_float4(v.x * s, v.y * s, v.z * s, v.w * s);
            *(float4*)&As[m][j] = w;
        }
    }
    __syncthreads();

    const int tx = tid & 15;   // 16 col-groups
    const int ty = tid >> 4;   // 16 row-groups
    float acc[4][4] = {};
    #pragma unroll 8
    for (int k = 0; k < 128; ++k) {
        float a0 = As[ty * 4 + 0][k];
        float a1 = As[ty * 4 + 1][k];
        float a2 = As[ty * 4 + 2][k];
        float a3 = As[ty * 4 + 3][k];
        float4 b = *(float4*)&Bs[k][tx * 4];
        acc[0][0] += a0 * b.x; acc[0][1] += a0 * b.y; acc[0][2] += a0 * b.z; acc[0][3] += a0 * b.w;
        acc[1][0] += a1 * b.x; acc[1][1] += a1 * b.y; acc[1][2] += a1 * b.z; acc[1][3] += a1 * b.w;
        acc[2][0] += a2 * b.x; acc[2][1] += a2 * b.y; acc[2][2] += a2 * b.z; acc[2][3] += a2 * b.w;
        acc[3][0] += a3 * b.x; acc[3][1] += a3 * b.y; acc[3][2] += a3 * b.z; acc[3][3] += a3 * b.w;
    }

    const int colbase = cb * 64 + tx * 4;
    float4 bias = make_float4(0.f, 0.f, 0.f, 0.f);
    if (colbias) bias = *(const float4*)(colbias + colbase);
    #pragma unroll
    for (int i = 0; i < 4; ++i) {
        int row = row0 + ty * 4 + i;
        if (row < M) {
            float* cp = C + (size_t)row * 128 + colbase;
            float4 r = make_float4(acc[i][0] + bias.x, acc[i][1] + bias.y,
                                   acc[i][2] + bias.z, acc[i][3] + bias.w);
            if (accumulate) {
                float4 old = *(float4*)cp;
                r.x += old.x; r.y += old.y; r.z += old.z; r.w += old.w;
            }
            *(float4*)cp = r;
        }
    }
}

// ---------------------------------------------------------------------------
// K6: CSC aggregation + norm_dst + (bias) + BN + ReLU, one wave per dst node,
// float2 per lane (64 lanes x 8B = full 512B row, coalesced gather).
__global__ __launch_bounds__(256) void aggregate_kernel(
    const float* __restrict__ hw, const int* __restrict__ offs, const int* __restrict__ csc,
    const float* __restrict__ norm_dst, const float* __restrict__ bias,
    const float* __restrict__ gamma, const float* __restrict__ beta,
    const float* __restrict__ mean, const float* __restrict__ var,
    float* __restrict__ hout, int n) {
    const int lane = threadIdx.x & 63;
    const int gw = (blockIdx.x * blockDim.x + threadIdx.x) >> 6;
    const int nw = (gridDim.x * blockDim.x) >> 6;
    const int c = lane * 2;

    // hoist per-column constants
    const float sc0 = gamma[c] * rsqrtf(var[c] + EPS);
    const float sc1 = gamma[c + 1] * rsqrtf(var[c + 1] + EPS);
    const float mn0 = mean[c], mn1 = mean[c + 1];
    const float bt0 = beta[c], bt1 = beta[c + 1];
    const float bi0 = bias ? bias[c] : 0.f;
    const float bi1 = bias ? bias[c + 1] : 0.f;

    for (int v = gw; v < n; v += nw) {
        int e0 = offs[v], e1 = offs[v + 1];
        float2 acc = make_float2(0.f, 0.f);
        int e = e0;
        for (; e + 2 <= e1; e += 2) {
            int s0 = csc[e], s1 = csc[e + 1];
            float2 p0 = *(const float2*)(hw + (size_t)s0 * 128 + c);
            float2 p1 = *(const float2*)(hw + (size_t)s1 * 128 + c);
            acc.x += p0.x + p1.x;
            acc.y += p0.y + p1.y;
        }
        if (e < e1) {
            int s0 = csc[e];
            float2 p0 = *(const float2*)(hw + (size_t)s0 * 128 + c);
            acc.x += p0.x; acc.y += p0.y;
        }
        float nd = norm_dst[v];
        float h0 = acc.x * nd + bi0;
        float h1 = acc.y * nd + bi1;
        h0 = fmaxf((h0 - mn0) * sc0 + bt0, 0.f);
        h1 = fmaxf((h1 - mn1) * sc1 + bt1, 0.f);
        *(float2*)(hout + (size_t)v * 128 + c) = make_float2(h0, h1);
    }
}

// ---------------------------------------------------------------------------
// K7: final classifier: z = relu(BN0(cls_acc)); out = z @ W1 + b1
__global__ __launch_bounds__(256) void classifier_final_kernel(
    const float* __restrict__ acc,
    const float* __restrict__ g, const float* __restrict__ bt,
    const float* __restrict__ mn, const float* __restrict__ vr,
    const float* __restrict__ W1, const float* __restrict__ b1,
    float* __restrict__ out, int n) {
    __shared__ float W1s[128 * 47];
    __shared__ float zbuf[4][128];
    const int tid = threadIdx.x, lane = tid & 63, wid = tid >> 6;
    for (int idx = tid; idx < 128 * 47; idx += 256) W1s[idx] = W1[idx];
    __syncthreads();

    const int c0 = lane * 2;
    const float sc0 = g[c0] * rsqrtf(vr[c0] + EPS);
    const float sc1 = g[c0 + 1] * rsqrtf(vr[c0 + 1] + EPS);
    const float m0 = mn[c0], m1 = mn[c0 + 1];
    const float be0 = bt[c0], be1 = bt[c0 + 1];
    const float bb = (lane < 47) ? b1[lane] : 0.f;

    const int gw = blockIdx.x * 4 + wid;
    const int nw = gridDim.x * 4;
    for (int row = gw; row < n; row += nw) {
        float2 a = *(const float2*)(acc + (size_t)row * 128 + c0);
        zbuf[wid][c0]     = fmaxf((a.x - m0) * sc0 + be0, 0.f);
        zbuf[wid][c0 + 1] = fmaxf((a.y - m1) * sc1 + be1, 0.f);
        // wave-internal LDS write->read: DS ops issue in order within a wave
        float o = 0.f;
        if (lane < 47) {
            #pragma unroll 8
            for (int k = 0; k < 128; ++k) o += zbuf[wid][k] * W1s[k * 47 + lane];
            out[(size_t)row * 47 + lane] = o + bb;
        }
    }
}

// ---------------------------------------------------------------------------
extern "C" void kernel_launch(void* const* d_in, const int* in_sizes, int n_in,
                              void* d_out, int out_size, void* d_ws, size_t ws_size,
                              hipStream_t stream) {
    const float* feat     = (const float*)d_in[0];
    const int*   src      = (const int*)d_in[1];
    const int*   dst      = (const int*)d_in[2];
    const float* enc_W    = (const float*)d_in[3];
    const float* enc_bias = (const float*)d_in[4];
    const float* bn_gamma = (const float*)d_in[5];
    const float* bn_beta  = (const float*)d_in[6];
    const float* bn_mean  = (const float*)d_in[7];
    const float* bn_var   = (const float*)d_in[8];
    const float* cls_W0   = (const float*)d_in[9];
    const float* cls_b0   = (const float*)d_in[10];
    const float* cls_g0   = (const float*)d_in[11];
    const float* cls_be0  = (const float*)d_in[12];
    const float* cls_m0   = (const float*)d_in[13];
    const float* cls_v0   = (const float*)d_in[14];
    const float* cls_W1   = (const float*)d_in[15];
    const float* cls_b1   = (const float*)d_in[16];
    float* out = (float*)d_out;

    const int N_ = in_sizes[0] / 128;
    const int E_ = in_sizes[1];

    char* p = (char*)d_ws;
    auto alloc = [&](size_t bytes) {
        char* r = p;
        p += (bytes + 255) & ~(size_t)255;
        return r;
    };
    float* h_a      = (float*)alloc((size_t)N_ * 128 * 4);
    float* h_b      = (float*)alloc((size_t)N_ * 128 * 4);
    float* cls_acc  = (float*)alloc((size_t)N_ * 128 * 4);
    float* norm_src = (float*)alloc((size_t)N_ * 4);
    float* norm_dst = (float*)alloc((size_t)N_ * 4);
    int* outdeg     = (int*)alloc((size_t)N_ * 4);
    int* indeg      = (int*)alloc((size_t)N_ * 4);
    int* cursor     = (int*)alloc((size_t)N_ * 4);
    int* offs       = (int*)alloc((size_t)(N_ + 1) * 4);
    int* csc        = (int*)alloc((size_t)E_ * 4);

    hipMemsetAsync(outdeg, 0, (size_t)N_ * 4, stream);
    hipMemsetAsync(indeg, 0, (size_t)N_ * 4, stream);
    hipMemsetAsync(cursor, 0, (size_t)N_ * 4, stream);

    const int eb = (E_ + 255) / 256;
    degrees_kernel<<<eb, 256, 0, stream>>>(src, dst, outdeg, indeg, E_);
    norms_kernel<<<(N_ + 255) / 256, 256, 0, stream>>>(outdeg, indeg, norm_src, norm_dst, N_);
    scan_offsets_kernel<<<1, 1024, 0, stream>>>(indeg, offs, N_);
    fill_csc_kernel<<<eb, 256, 0, stream>>>(src, dst, offs, cursor, csc, E_);

    dim3 ggrid((N_ + 63) / 64, 2);
    const int agg_blocks = (N_ + 3) / 4;   // 4 waves/block, 1 node/wave

    for (int i = 0; i < 4; ++i) {
        const float* hin = (i == 0) ? feat : h_a;
        gemm128_kernel<<<ggrid, 256, 0, stream>>>(
            hin, enc_W + (size_t)i * 128 * 128, h_b, norm_src, nullptr, N_, 0);
        aggregate_kernel<<<agg_blocks, 256, 0, stream>>>(
            h_b, offs, csc, norm_dst,
            (i == 3) ? enc_bias : nullptr,
            bn_gamma + i * 128, bn_beta + i * 128, bn_mean + i * 128, bn_var + i * 128,
            h_a, N_);
        gemm128_kernel<<<ggrid, 256, 0, stream>>>(
            h_a, cls_W0 + (size_t)i * 128 * 128, cls_acc, nullptr,
            (i == 0) ? cls_b0 : nullptr, N_, (i == 0) ? 0 : 1);
    }
    classifier_final_kernel<<<(N_ + 15) / 16, 256, 0, stream>>>(
        cls_acc, cls_g0, cls_be0, cls_m0, cls_v0, cls_W1, cls_b1, out, N_);
}